// Round 7
// baseline (254.844 us; speedup 1.0000x reference)
//
#include <hip/hip_runtime.h>
#include <math.h>

#define B 32
#define T 2048
#define H 512

#define BT2 128            // t rows per k2 block
#define ASTR 520           // LDS row stride for A (bf16 elems); 1040B mod 128 = 16 -> benign

typedef __attribute__((ext_vector_type(8))) __bf16 bf16x8;
typedef __attribute__((ext_vector_type(4))) __bf16 bf16x4v;
typedef __attribute__((ext_vector_type(4))) float f32x4;
typedef __attribute__((ext_vector_type(4))) float floatx4;

union pack8 { bf16x4v h; uint2 u; };

// ---------------- K_init: flat grid, 545 blocks. (unchanged from r6)
__global__ __launch_bounds__(256) void k_init(const float* __restrict__ query,
                                              const float* __restrict__ q_w,
                                              const float* __restrict__ bias,
                                              const float* __restrict__ v_w,
                                              float* __restrict__ qpb,
                                              unsigned short* __restrict__ wbf,
                                              float* __restrict__ ctx_num,
                                              float* __restrict__ denom) {
    const int blk = blockIdx.x;
    const int tid = threadIdx.x;

    if (blk >= 544) {
#pragma unroll
        for (int i = 0; i < 16; ++i) {
            const int off = tid * 4 + i * 1024;
            *(f32x4*)(ctx_num + off) = (f32x4){0.f, 0.f, 0.f, 0.f};
        }
        if (tid < B) denom[tid] = 0.f;
        return;
    }
    if (blk >= 512) {
        const int c2 = blk - 512;            // 0..31 -> (strip = c2>>2, ni = c2&3)
        const int wv = tid >> 6;
        const int lane = tid & 63;
        const int srow = (c2 >> 2) * 64 + (c2 & 3) * 16 + (lane & 15);
        const int scol0 = (lane >> 4) * 8;
#pragma unroll
        for (int kk = 0; kk < 4; ++kk) {
            const int k = wv * 4 + kk;
            const float* src = v_w + (size_t)srow * H + k * 32 + scol0;
            f32x4 a0 = *(const f32x4*)src;
            f32x4 a1 = *(const f32x4*)(src + 4);
            pack8 p0, p1;
            p0.h = __builtin_convertvector(a0, bf16x4v);
            p1.h = __builtin_convertvector(a1, bf16x4v);
            uint4 u = {p0.u.x, p0.u.y, p1.u.x, p1.u.y};
            *(uint4*)(wbf + ((size_t)c2 * 16 + k) * 512 + lane * 8) = u;
        }
        return;
    }

    const int b = blk >> 4;
    const int s = blk & 15;
    const int wave = tid >> 6;
    const int lane = tid & 63;

    const float* qb = query + (size_t)b * H + lane * 8;
    float4 q0 = *(const float4*)qb;
    float4 q1 = *(const float4*)(qb + 4);

    const int o0 = s * 32 + wave * 8;
#pragma unroll
    for (int i = 0; i < 8; ++i) {
        const int o = o0 + i;
        const float* wr = q_w + (size_t)o * H + lane * 8;
        float4 w0 = *(const float4*)wr;
        float4 w1 = *(const float4*)(wr + 4);
        float acc = w0.x * q0.x + w0.y * q0.y + w0.z * q0.z + w0.w * q0.w +
                    w1.x * q1.x + w1.y * q1.y + w1.z * q1.z + w1.w * q1.w;
#pragma unroll
        for (int m = 1; m < 64; m <<= 1) acc += __shfl_xor(acc, m);
        if (lane == 0) qpb[b * H + o] = acc + bias[o];
    }
}

// ---------------- K2: 128t x 512o per block; score + sigmoid + ctx partial, fused.
// v7: BT2=128 (32 MFMA/k-step latency cover, B-panel L2 traffic halved again),
//     A staged in 4 k-chunks of 128 cols with register staging (issue loads for
//     chunk c+1 BEFORE computing chunk c; cvt+ds_write after -> HBM latency
//     hidden under MFMA; only 4 barriers/block). B: depth-1 register prefetch
//     from fragment-ordered global wbf, crossing chunk boundaries.
//     1 block/CU (133KB LDS), 2 waves/SIMD, launch_bounds(512,2) = 256-reg cap.
__global__ __launch_bounds__(512, 2) void k2_fused(const float* __restrict__ value,
                                                   const unsigned short* __restrict__ wbf,
                                                   const float* __restrict__ la,
                                                   const float* __restrict__ conv_w,
                                                   const float* __restrict__ conv_b,
                                                   const float* __restrict__ s_w,
                                                   const float* __restrict__ qpb,
                                                   const float* __restrict__ s_b,
                                                   float* __restrict__ pre_sg,
                                                   float* __restrict__ ctx_num,
                                                   float* __restrict__ denom) {
    __shared__ __align__(16) unsigned short As[BT2 * ASTR];   // 133120 B
    __shared__ float las[BT2 + 2];
    __shared__ float redp[BT2][9];                            // 4608 B
    __shared__ float sgs[BT2];
    __shared__ float redc[4][H];                              // 8 KB
    // total ~147 KB -> 1 block/CU

    const int t0 = blockIdx.x * BT2;
    const int b  = blockIdx.y;
    const int tid = threadIdx.x;
    const int wave = tid >> 6;        // 0..7
    const int lane = tid & 63;
    const int tx   = lane & 15;
    const int quad = lane >> 4;
    const int wn   = wave * 64;       // this wave's o-strip

    if (tid < BT2 + 2) {
        const int t = t0 + tid - 1;
        las[tid] = (t >= 0 && t < T) ? la[b * T + t] : 0.f;
    }

    // staging geometry: thread -> row tid>>2 (0..127), 32 floats at (tid&3)*32
    const int srow = tid >> 2;
    const int scol = (tid & 3) * 32;
    const float* sgp = value + ((size_t)b * T + t0 + srow) * H + scol;
    unsigned short* slp = &As[srow * ASTR + scol];

    // ---- prologue: stage chunk 0 (cols 0..127)
    {
        f32x4 r[8];
#pragma unroll
        for (int i = 0; i < 8; ++i) r[i] = *(const f32x4*)(sgp + i * 4);
#pragma unroll
        for (int i = 0; i < 4; ++i) {
            pack8 p0, p1;
            p0.h = __builtin_convertvector(r[2 * i], bf16x4v);
            p1.h = __builtin_convertvector(r[2 * i + 1], bf16x4v);
            uint4 u = {p0.u.x, p0.u.y, p1.u.x, p1.u.y};
            *(uint4*)(slp + i * 8) = u;
        }
    }
    __syncthreads();

    floatx4 acc[8][4];
#pragma unroll
    for (int i = 0; i < 8; ++i)
#pragma unroll
        for (int j = 0; j < 4; ++j) acc[i][j] = (floatx4){0.f, 0.f, 0.f, 0.f};

    // B fragments: halfword index ((wave*4+ni)*16 + k)*512 + lane*8
    const unsigned short* gB = wbf + (size_t)wave * 32768 + lane * 8;
    const unsigned short* aBlo = &As[tx * ASTR + quad * 8];            // rows 0..63
    const unsigned short* aBhi = aBlo + 64 * ASTR;                     // rows 64..127

    bf16x8 bcur[4], bnxt[4];
#pragma unroll
    for (int ni = 0; ni < 4; ++ni)
        bcur[ni] = *(const bf16x8*)(gB + ni * 8192);

    // ---- main loop: 4 chunks x 4 k-steps
#pragma unroll
    for (int c = 0; c < 4; ++c) {
        // T14 issue-early: global loads for chunk c+1 (held in regs across compute)
        f32x4 srg[8];
        if (c < 3) {
#pragma unroll
            for (int i = 0; i < 8; ++i)
                srg[i] = *(const f32x4*)(sgp + (c + 1) * 128 + i * 4);
        }

#pragma unroll
        for (int kk = 0; kk < 4; ++kk) {
            const int k = c * 4 + kk;
            if (k < 15) {
#pragma unroll
                for (int ni = 0; ni < 4; ++ni)
                    bnxt[ni] = *(const bf16x8*)(gB + ni * 8192 + (k + 1) * 512);
            }
            bf16x8 af[8];
#pragma unroll
            for (int mi = 0; mi < 4; ++mi)
                af[mi] = *(const bf16x8*)(aBlo + mi * 16 * ASTR + k * 32);
#pragma unroll
            for (int mi = 0; mi < 4; ++mi)
                af[mi + 4] = *(const bf16x8*)(aBhi + mi * 16 * ASTR + k * 32);
#pragma unroll
            for (int mi = 0; mi < 8; ++mi)
#pragma unroll
                for (int ni = 0; ni < 4; ++ni)
                    acc[mi][ni] = __builtin_amdgcn_mfma_f32_16x16x32_bf16(
                        af[mi], bcur[ni], acc[mi][ni], 0, 0, 0);
            if (k < 15) {
#pragma unroll
                for (int ni = 0; ni < 4; ++ni) bcur[ni] = bnxt[ni];
            }
        }

        // T14 write-late: cvt + ds_write chunk c+1, then one barrier
        if (c < 3) {
#pragma unroll
            for (int i = 0; i < 4; ++i) {
                pack8 p0, p1;
                p0.h = __builtin_convertvector(srg[2 * i], bf16x4v);
                p1.h = __builtin_convertvector(srg[2 * i + 1], bf16x4v);
                uint4 u = {p0.u.x, p0.u.y, p1.u.x, p1.u.y};
                *(uint4*)(slp + (c + 1) * 128 + i * 8) = u;
            }
            __syncthreads();
        }
    }

    // per-lane epilogue constants (loaded after the loop: reg pressure)
    float qp4[4], sw4[4], cb4[4], c04[4], c14[4], c24[4];
#pragma unroll
    for (int ni = 0; ni < 4; ++ni) {
        const int ol = wn + ni * 16 + tx;
        qp4[ni] = qpb[b * H + ol];
        sw4[ni] = s_w[ol];
        cb4[ni] = conv_b[ol];
        c04[ni] = conv_w[ol * 3 + 0];
        c14[ni] = conv_w[ol * 3 + 1];
        c24[ni] = conv_w[ol * 3 + 2];
    }

    // epilogue: tanh + s_w reduce over this wave's 64 o
    float sacc[32];
#pragma unroll
    for (int i = 0; i < 32; ++i) sacc[i] = 0.f;
#pragma unroll
    for (int ni = 0; ni < 4; ++ni) {
#pragma unroll
        for (int mi = 0; mi < 8; ++mi)
#pragma unroll
            for (int r = 0; r < 4; ++r) {
                const int tl = mi * 16 + quad * 4 + r;
                const float conv = c04[ni] * las[tl] + c14[ni] * las[tl + 1] +
                                   c24[ni] * las[tl + 2] + cb4[ni];
                const float x = acc[mi][ni][r] + qp4[ni] + conv;
                const float ex = __expf(2.f * x);
                const float th = 1.f - 2.f * __builtin_amdgcn_rcpf(ex + 1.f);
                sacc[mi * 4 + r] += sw4[ni] * th;
            }
    }
#pragma unroll
    for (int i = 0; i < 32; ++i) {
        float v = sacc[i];
        v += __shfl_xor(v, 1);
        v += __shfl_xor(v, 2);
        v += __shfl_xor(v, 4);
        v += __shfl_xor(v, 8);
        if (tx == 0) redp[(i >> 2) * 16 + quad * 4 + (i & 3)][wave] = v;
    }
    __syncthreads();

    // first 128 threads (waves 0,1): score -> sigmoid -> sgs + pre_sg + denom
    if (tid < BT2) {
        float sc = s_b[0];
#pragma unroll
        for (int w = 0; w < 8; ++w) sc += redp[tid][w];
        const float sg = 1.f / (1.f + __expf(-sc));
        sgs[tid] = sg;
        pre_sg[b * T + t0 + tid] = sg;
        float dsum = sg;
#pragma unroll
        for (int m = 1; m < 64; m <<= 1) dsum += __shfl_xor(dsum, m);
        if (lane == 0) atomicAdd(&denom[b], dsum);
    }
    __syncthreads();                  // sgs visible

    // ctx partial from the staged bf16 A-tile (no value re-read)
    {
        const int h4 = (tid & 127) * 4;
        const int tp = tid >> 7;          // 0..3
        f32x4 a = {0.f, 0.f, 0.f, 0.f};
        for (int t = tp; t < BT2; t += 4) {
            const float w = sgs[t];
            bf16x4v hv = *(const bf16x4v*)&As[t * ASTR + h4];
            f32x4 v = __builtin_convertvector(hv, f32x4);
            a.x += w * v.x; a.y += w * v.y; a.z += w * v.z; a.w += w * v.w;
        }
        *(f32x4*)&redc[tp][h4] = a;
    }
    __syncthreads();
    if (tid < 128) {
        const int h = tid * 4;
        f32x4 r0 = *(const f32x4*)&redc[0][h];
        f32x4 r1 = *(const f32x4*)&redc[1][h];
        f32x4 r2 = *(const f32x4*)&redc[2][h];
        f32x4 r3 = *(const f32x4*)&redc[3][h];
        atomicAdd(&ctx_num[b * H + h + 0], r0.x + r1.x + r2.x + r3.x);
        atomicAdd(&ctx_num[b * H + h + 1], r0.y + r1.y + r2.y + r3.y);
        atomicAdd(&ctx_num[b * H + h + 2], r0.z + r1.z + r2.z + r3.z);
        atomicAdd(&ctx_num[b * H + h + 3], r0.w + r1.w + r2.w + r3.w);
    }
}

// ---------------- K3: scale by 1/denom. (unchanged from r6)
__global__ __launch_bounds__(256) void k3_scale(const float* __restrict__ pre_sg,
                                                const float* __restrict__ ctx_num,
                                                const float* __restrict__ denom,
                                                float* __restrict__ attn_out,
                                                float* __restrict__ ctx) {
    const int bx = blockIdx.x;        // 0..7
    const int b  = blockIdx.y;        // 0..31
    const int tid = threadIdx.x;
    const float inv = 1.f / denom[b];
    const int t = bx * 256 + tid;
    attn_out[b * T + t] = pre_sg[b * T + t] * inv;
    if (tid < 64) {
        const int h = bx * 64 + tid;
        ctx[b * H + h] = ctx_num[b * H + h] * inv;
    }
}

extern "C" void kernel_launch(void* const* d_in, const int* in_sizes, int n_in,
                              void* d_out, int out_size, void* d_ws, size_t ws_size,
                              hipStream_t stream) {
    const float* query  = (const float*)d_in[0];
    const float* value  = (const float*)d_in[1];
    const float* la     = (const float*)d_in[2];
    const float* conv_w = (const float*)d_in[3];
    const float* conv_b = (const float*)d_in[4];
    const float* q_w    = (const float*)d_in[5];
    const float* v_w    = (const float*)d_in[6];
    const float* s_w    = (const float*)d_in[7];
    const float* s_b    = (const float*)d_in[8];
    const float* bias   = (const float*)d_in[9];

    float* out  = (float*)d_out;
    float* ctx  = out;            // (B, H)
    float* attn = out + B * H;    // (B, T)

    float* qpb     = (float*)d_ws;                 // B*H
    float* pre_sg  = qpb + B * H;                  // B*T
    float* ctx_num = pre_sg + B * T;               // B*H
    float* denom   = ctx_num + B * H;              // 64
    unsigned short* wbf = (unsigned short*)(denom + 64);   // H*H bf16, fragment-ordered

    k_init<<<545, 256, 0, stream>>>(query, q_w, bias, v_w, qpb, wbf, ctx_num, denom);

    dim3 g2(T / BT2, B);
    k2_fused<<<g2, 512, 0, stream>>>(value, wbf, la, conv_w, conv_b, s_w, qpb, s_b,
                                     pre_sg, ctx_num, denom);

    dim3 g3(8, B);
    k3_scale<<<g3, 256, 0, stream>>>(pre_sg, ctx_num, denom, attn, ctx);
}

// Round 9
// 249.301 us; speedup vs baseline: 1.0222x; 1.0222x over previous
//
#include <hip/hip_runtime.h>
#include <math.h>

#define B 32
#define T 2048
#define H 512

#define BT2 64             // t rows per k2 block
#define ASTR 520           // LDS row stride for A (bf16 elems)

typedef __attribute__((ext_vector_type(8))) __bf16 bf16x8;
typedef __attribute__((ext_vector_type(4))) __bf16 bf16x4v;
typedef __attribute__((ext_vector_type(4))) float f32x4;
typedef __attribute__((ext_vector_type(4))) float floatx4;

union pack8 { bf16x4v h; uint2 u; };

// ---------------- K_init: flat grid, 545 blocks.
// blocks [0,512): GEMV q-proj. b=blk>>4, s=blk&15 (32 outputs, 8/wave)
// blocks [512,544): convert v_w slice -> bf16, FRAGMENT-ORDERED (nt loads:
//   one-pass stream, keep L2 clean)
// block 544: zero ctx_num (B*H) and denom (B)
__global__ __launch_bounds__(256) void k_init(const float* __restrict__ query,
                                              const float* __restrict__ q_w,
                                              const float* __restrict__ bias,
                                              const float* __restrict__ v_w,
                                              float* __restrict__ qpb,
                                              unsigned short* __restrict__ wbf,
                                              float* __restrict__ ctx_num,
                                              float* __restrict__ denom) {
    const int blk = blockIdx.x;
    const int tid = threadIdx.x;

    if (blk >= 544) {
#pragma unroll
        for (int i = 0; i < 16; ++i) {
            const int off = tid * 4 + i * 1024;
            *(f32x4*)(ctx_num + off) = (f32x4){0.f, 0.f, 0.f, 0.f};
        }
        if (tid < B) denom[tid] = 0.f;
        return;
    }
    if (blk >= 512) {
        const int c2 = blk - 512;            // 0..31 -> (strip = c2>>2, ni = c2&3)
        const int wv = tid >> 6;
        const int lane = tid & 63;
        const int srow = (c2 >> 2) * 64 + (c2 & 3) * 16 + (lane & 15);
        const int scol0 = (lane >> 4) * 8;
#pragma unroll
        for (int kk = 0; kk < 4; ++kk) {
            const int k = wv * 4 + kk;
            const float* src = v_w + (size_t)srow * H + k * 32 + scol0;
            f32x4 a0 = __builtin_nontemporal_load((const f32x4*)src);
            f32x4 a1 = __builtin_nontemporal_load((const f32x4*)(src + 4));
            pack8 p0, p1;
            p0.h = __builtin_convertvector(a0, bf16x4v);
            p1.h = __builtin_convertvector(a1, bf16x4v);
            uint4 u = {p0.u.x, p0.u.y, p1.u.x, p1.u.y};
            *(uint4*)(wbf + ((size_t)c2 * 16 + k) * 512 + lane * 8) = u;
        }
        return;
    }

    const int b = blk >> 4;
    const int s = blk & 15;
    const int wave = tid >> 6;
    const int lane = tid & 63;

    const float* qb = query + (size_t)b * H + lane * 8;
    f32x4 q0 = *(const f32x4*)qb;
    f32x4 q1 = *(const f32x4*)(qb + 4);

    const int o0 = s * 32 + wave * 8;
#pragma unroll
    for (int i = 0; i < 8; ++i) {
        const int o = o0 + i;
        const float* wr = q_w + (size_t)o * H + lane * 8;
        f32x4 w0 = __builtin_nontemporal_load((const f32x4*)wr);
        f32x4 w1 = __builtin_nontemporal_load((const f32x4*)(wr + 4));
        float acc = w0.x * q0.x + w0.y * q0.y + w0.z * q0.z + w0.w * q0.w +
                    w1.x * q1.x + w1.y * q1.y + w1.z * q1.z + w1.w * q1.w;
#pragma unroll
        for (int m = 1; m < 64; m <<= 1) acc += __shfl_xor(acc, m);
        if (lane == 0) qpb[b * H + o] = acc + bias[o];
    }
}

// ---------------- K2: 64t x 512o per block; score + sigmoid + ctx partial, fused.
// v8: identical to the proven 90us r5/r6 structure (BT2=64, barrier-free K-loop,
//     depth-1 register B prefetch, LDS-A staged once, ctx from bf16 A-tile),
//     PLUS nontemporal value loads: the 134MB value stream was evicting the
//     512KB L2-resident wbf B-panel, turning every B load into an L3 round-trip
//     (~600-900cy, uncoverable at depth-1). nt keeps wbf L2-hot.
__global__ __launch_bounds__(512, 4) void k2_fused(const float* __restrict__ value,
                                                   const unsigned short* __restrict__ wbf,
                                                   const float* __restrict__ la,
                                                   const float* __restrict__ conv_w,
                                                   const float* __restrict__ conv_b,
                                                   const float* __restrict__ s_w,
                                                   const float* __restrict__ qpb,
                                                   const float* __restrict__ s_b,
                                                   float* __restrict__ pre_sg,
                                                   float* __restrict__ ctx_num,
                                                   float* __restrict__ denom) {
    __shared__ __align__(16) unsigned short As[BT2 * ASTR];   // 66560 B
    __shared__ float las[BT2 + 2];
    __shared__ float redp[BT2][9];
    __shared__ float sgs[BT2];
    __shared__ float redc[4][H];                              // 8 KB

    const int t0 = blockIdx.x * BT2;
    const int b  = blockIdx.y;
    const int tid = threadIdx.x;
    const int wave = tid >> 6;        // 0..7
    const int lane = tid & 63;
    const int tx   = lane & 15;
    const int quad = lane >> 4;
    const int wn   = wave * 64;       // this wave's o-strip

    if (tid < BT2 + 2) {
        const int t = t0 + tid - 1;
        las[tid] = (t >= 0 && t < T) ? la[b * T + t] : 0.f;
    }

    // ---- stage A tile (64 rows x 512 cols f32 -> bf16), whole K, once.
    // NONTEMPORAL: value is a pure stream (each byte read exactly once).
    {
        const int srow = tid >> 3;            // 0..63
        const int scol = (tid & 7) * 8;       // 0..56
        const float* sg = value + ((size_t)b * T + t0 + srow) * H + scol;
        unsigned short* sl = &As[srow * ASTR + scol];
#pragma unroll
        for (int c = 0; c < 8; ++c) {
            f32x4 a0 = __builtin_nontemporal_load((const f32x4*)(sg + c * 64));
            f32x4 a1 = __builtin_nontemporal_load((const f32x4*)(sg + c * 64 + 4));
            pack8 p0, p1;
            p0.h = __builtin_convertvector(a0, bf16x4v);
            p1.h = __builtin_convertvector(a1, bf16x4v);
            uint4 u = {p0.u.x, p0.u.y, p1.u.x, p1.u.y};
            *(uint4*)(sl + c * 64) = u;
        }
    }
    __syncthreads();                  // the only barrier before the epilogue

    floatx4 acc[4][4];
#pragma unroll
    for (int i = 0; i < 4; ++i)
#pragma unroll
        for (int j = 0; j < 4; ++j) acc[i][j] = (floatx4){0.f, 0.f, 0.f, 0.f};

    // B fragments: halfword index ((wave*4+ni)*16 + k)*512 + lane*8
    const unsigned short* gB = wbf + (size_t)wave * 32768 + lane * 8;
    const unsigned short* aB = &As[tx * ASTR + quad * 8];

    // ---- barrier-free K-loop, fully unrolled, explicit depth-1 B prefetch
    bf16x8 bcur[4], bnxt[4];
#pragma unroll
    for (int ni = 0; ni < 4; ++ni)
        bcur[ni] = *(const bf16x8*)(gB + ni * 8192);

#pragma unroll
    for (int k = 0; k < 16; ++k) {
        if (k < 15) {
#pragma unroll
            for (int ni = 0; ni < 4; ++ni)
                bnxt[ni] = *(const bf16x8*)(gB + ni * 8192 + (k + 1) * 512);
        }
        bf16x8 af[4];
#pragma unroll
        for (int mi = 0; mi < 4; ++mi)
            af[mi] = *(const bf16x8*)(aB + mi * 16 * ASTR + k * 32);
#pragma unroll
        for (int mi = 0; mi < 4; ++mi)
#pragma unroll
            for (int ni = 0; ni < 4; ++ni)
                acc[mi][ni] = __builtin_amdgcn_mfma_f32_16x16x32_bf16(
                    af[mi], bcur[ni], acc[mi][ni], 0, 0, 0);
        if (k < 15) {
#pragma unroll
            for (int ni = 0; ni < 4; ++ni) bcur[ni] = bnxt[ni];
        }
    }

    // per-lane epilogue constants (loaded after the loop: reg pressure)
    float qp4[4], sw4[4], cb4[4], c04[4], c14[4], c24[4];
#pragma unroll
    for (int ni = 0; ni < 4; ++ni) {
        const int ol = wn + ni * 16 + tx;
        qp4[ni] = qpb[b * H + ol];
        sw4[ni] = s_w[ol];
        cb4[ni] = conv_b[ol];
        c04[ni] = conv_w[ol * 3 + 0];
        c14[ni] = conv_w[ol * 3 + 1];
        c24[ni] = conv_w[ol * 3 + 2];
    }

    // epilogue: tanh + s_w reduce over this wave's 64 o
    float sacc[16];
#pragma unroll
    for (int i = 0; i < 16; ++i) sacc[i] = 0.f;
#pragma unroll
    for (int ni = 0; ni < 4; ++ni) {
#pragma unroll
        for (int mi = 0; mi < 4; ++mi)
#pragma unroll
            for (int r = 0; r < 4; ++r) {
                const int tl = mi * 16 + quad * 4 + r;
                const float conv = c04[ni] * las[tl] + c14[ni] * las[tl + 1] +
                                   c24[ni] * las[tl + 2] + cb4[ni];
                const float x = acc[mi][ni][r] + qp4[ni] + conv;
                const float ex = __expf(2.f * x);
                const float th = 1.f - 2.f * __builtin_amdgcn_rcpf(ex + 1.f);
                sacc[mi * 4 + r] += sw4[ni] * th;
            }
    }
#pragma unroll
    for (int i = 0; i < 16; ++i) {
        float v = sacc[i];
        v += __shfl_xor(v, 1);
        v += __shfl_xor(v, 2);
        v += __shfl_xor(v, 4);
        v += __shfl_xor(v, 8);
        if (tx == 0) redp[(i >> 2) * 16 + quad * 4 + (i & 3)][wave] = v;
    }
    __syncthreads();

    // first 64 threads: score -> sigmoid -> sgs + pre_sg + denom atomic
    if (tid < BT2) {
        float sc = s_b[0];
#pragma unroll
        for (int w = 0; w < 8; ++w) sc += redp[tid][w];
        const float sg = 1.f / (1.f + __expf(-sc));
        sgs[tid] = sg;
        pre_sg[b * T + t0 + tid] = sg;
        float dsum = sg;
#pragma unroll
        for (int m = 1; m < 64; m <<= 1) dsum += __shfl_xor(dsum, m);
        if (tid == 0) atomicAdd(&denom[b], dsum);
    }
    __syncthreads();                  // sgs visible

    // ctx partial from the staged bf16 A-tile (no value re-read)
    {
        const int h4 = (tid & 127) * 4;
        const int tp = tid >> 7;          // 0..3
        f32x4 a = {0.f, 0.f, 0.f, 0.f};
        for (int t = tp; t < BT2; t += 4) {
            const float w = sgs[t];
            bf16x4v hv = *(const bf16x4v*)&As[t * ASTR + h4];
            f32x4 v = __builtin_convertvector(hv, f32x4);
            a.x += w * v.x; a.y += w * v.y; a.z += w * v.z; a.w += w * v.w;
        }
        *(f32x4*)&redc[tp][h4] = a;
    }
    __syncthreads();
    if (tid < 128) {
        const int h = tid * 4;
        f32x4 r0 = *(const f32x4*)&redc[0][h];
        f32x4 r1 = *(const f32x4*)&redc[1][h];
        f32x4 r2 = *(const f32x4*)&redc[2][h];
        f32x4 r3 = *(const f32x4*)&redc[3][h];
        atomicAdd(&ctx_num[b * H + h + 0], r0.x + r1.x + r2.x + r3.x);
        atomicAdd(&ctx_num[b * H + h + 1], r0.y + r1.y + r2.y + r3.y);
        atomicAdd(&ctx_num[b * H + h + 2], r0.z + r1.z + r2.z + r3.z);
        atomicAdd(&ctx_num[b * H + h + 3], r0.w + r1.w + r2.w + r3.w);
    }
}

// ---------------- K3: scale by 1/denom. 256 blocks: (bx 0..7, b 0..31).
__global__ __launch_bounds__(256) void k3_scale(const float* __restrict__ pre_sg,
                                                const float* __restrict__ ctx_num,
                                                const float* __restrict__ denom,
                                                float* __restrict__ attn_out,
                                                float* __restrict__ ctx) {
    const int bx = blockIdx.x;        // 0..7
    const int b  = blockIdx.y;        // 0..31
    const int tid = threadIdx.x;
    const float inv = 1.f / denom[b];
    const int t = bx * 256 + tid;
    attn_out[b * T + t] = pre_sg[b * T + t] * inv;
    if (tid < 64) {
        const int h = bx * 64 + tid;
        ctx[b * H + h] = ctx_num[b * H + h] * inv;
    }
}

extern "C" void kernel_launch(void* const* d_in, const int* in_sizes, int n_in,
                              void* d_out, int out_size, void* d_ws, size_t ws_size,
                              hipStream_t stream) {
    const float* query  = (const float*)d_in[0];
    const float* value  = (const float*)d_in[1];
    const float* la     = (const float*)d_in[2];
    const float* conv_w = (const float*)d_in[3];
    const float* conv_b = (const float*)d_in[4];
    const float* q_w    = (const float*)d_in[5];
    const float* v_w    = (const float*)d_in[6];
    const float* s_w    = (const float*)d_in[7];
    const float* s_b    = (const float*)d_in[8];
    const float* bias   = (const float*)d_in[9];

    float* out  = (float*)d_out;
    float* ctx  = out;            // (B, H)
    float* attn = out + B * H;    // (B, T)

    float* qpb     = (float*)d_ws;                 // B*H
    float* pre_sg  = qpb + B * H;                  // B*T
    float* ctx_num = pre_sg + B * T;               // B*H
    float* denom   = ctx_num + B * H;              // 64
    unsigned short* wbf = (unsigned short*)(denom + 64);   // H*H bf16, fragment-ordered

    k_init<<<545, 256, 0, stream>>>(query, q_w, bias, v_w, qpb, wbf, ctx_num, denom);

    dim3 g2(T / BT2, B);
    k2_fused<<<g2, 512, 0, stream>>>(value, wbf, la, conv_w, conv_b, s_w, qpb, s_b,
                                     pre_sg, ctx_num, denom);

    dim3 g3(8, B);
    k3_scale<<<g3, 256, 0, stream>>>(pre_sg, ctx_num, denom, attn, ctx);
}